// Round 3
// baseline (1857.723 us; speedup 1.0000x reference)
//
#include <hip/hip_runtime.h>
#include <hip/hip_bf16.h>

// GCN 2-layer forward on MI355X (gfx950). fp32 in/out, int32 edges.
// Round 8: structural fusion via GCN linearity.
//   - Layer 2: sum_s h2[s] = (sum_s dinv[s] r1[s]) @ W2^T  -> gather r1 rows
//     directly, 64->40 matvec per node in LDS. k_gemm2 DELETED.
//   - CSR binB DELETED: gathers consume binA's 128-node bucket staging
//     directly. Per block: LDS fp32 acc[128][64], coalesced entry reads +
//     __shfl broadcast, 8-deep row-load ILP, ds_add_f32 accumulation.
//   - ebuf/rowptr/dinv arrays gone; degree = global atomic histogram in binA,
//     dinv = rsqrtf(deg+1) computed on the fly.
// Pipeline: cvtw -> binA -> gemm1 -> gath1 -> gath2 (5 kernels, was 7).

typedef __attribute__((ext_vector_type(8))) short bf16x8;   // 8 bf16 = 4 VGPRs
typedef __attribute__((ext_vector_type(4))) float f32x4;    // MFMA C/D

constexpr int NN = 100000;   // nodes
constexpr int NF = 512;      // input feats
constexpr int NH = 64;       // hidden
constexpr int NC = 40;       // classes
constexpr int NE = 1600000;  // edges

constexpr int NBUCK = 782;     // ceil(NN/128): bucket = dst >> 7
constexpr int CAP   = 3072;    // staging capacity/bucket (mean 2048, +22 sigma)
constexpr int ABLK  = 512;     // binA blocks
constexpr int CHUNK = NE / ABLK;  // 3125 edges/block (exact)

// ---- ws layout (byte offsets) ----
constexpr size_t OFF_DEG    = 0;           // int[NN] = 400KB
constexpr size_t OFF_GCUR   = 524288;      // int[1024] bucket totals (782 used)
constexpr size_t OFF_W1BF   = 1048576;     // bf16[64*512] = 64KB
constexpr size_t OFF_W2BF   = 1114112;     // bf16[40*64] = 5KB
constexpr size_t OFF_STAGE  = 2097152;     // int[NBUCK*CAP] = 9.61MB
constexpr size_t OFF_H1     = 12582912;    // bf16[NN*64] = 12.8MB
constexpr size_t OFF_R1     = 25690112;    // bf16[NN*64] = 12.8MB (pre-scaled r1)

// fp32 -> bf16 fragment helpers
__device__ inline short f2bs(float f) {
    union { __hip_bfloat16 h; short s; } u;
    u.h = __float2bfloat16(f);
    return u.s;
}
__device__ inline bf16x8 cvt8(const float* __restrict__ p) {
    bf16x8 r;
#pragma unroll
    for (int i = 0; i < 8; ++i) r[i] = f2bs(p[i]);
    return r;
}

// ---------------- W1/W2 fp32 -> bf16 (once) + zero deg/gcur ----------------
__global__ __launch_bounds__(256) void k_cvtw(const float* __restrict__ W1,
                                              const float* __restrict__ W2,
                                              __hip_bfloat16* __restrict__ W1bf,
                                              __hip_bfloat16* __restrict__ W2bf,
                                              int* __restrict__ gcur,
                                              int* __restrict__ deg) {
    int i = blockIdx.x * 256 + threadIdx.x;
    if (i < NH * NF) W1bf[i] = __float2bfloat16(W1[i]);
    if (i < NC * NH) W2bf[i] = __float2bfloat16(W2[i]);
    if (i < 1024) gcur[i] = 0;
    if (i < NN) deg[i] = 0;
}

// ---------------- binA: bucket edges by dst>>7 + degree histogram ----------
__global__ __launch_bounds__(256) void k_binA(const int* __restrict__ src,
                                              const int* __restrict__ dst,
                                              int* __restrict__ gcur,
                                              int* __restrict__ staging,
                                              int* __restrict__ deg) {
    __shared__ int cnt[NBUCK];
    __shared__ int base[NBUCK];
    __shared__ int cur[NBUCK];
    const int t = threadIdx.x;
    const int e0 = blockIdx.x * CHUNK;
    for (int i = t; i < NBUCK; i += 256) { cnt[i] = 0; cur[i] = 0; }
    __syncthreads();
    for (int i = t; i < CHUNK; i += 256) {
        int d = dst[e0 + i];
        atomicAdd(&cnt[d >> 7], 1);
        atomicAdd(&deg[d], 1);            // global degree histogram (L2-resident)
    }
    __syncthreads();
    for (int i = t; i < NBUCK; i += 256)
        base[i] = atomicAdd(&gcur[i], cnt[i]);   // reserve contiguous run
    __syncthreads();
    for (int i = t; i < CHUNK; i += 256) {
        int e = e0 + i;
        int d = dst[e];
        int b = d >> 7;
        int r = atomicAdd(&cur[b], 1);
        int pos = base[b] + r;
        if (pos < CAP)                            // deterministic input: never trips
            staging[b * CAP + pos] = ((d & 127) << 17) | src[e];
    }
}

// ---------------- GEMM1: h1s[NN,64] = (x @ W1^T) * dinv[row]  (bf16) ----
__global__ __launch_bounds__(256) void k_gemm1(const float* __restrict__ x,
                                               const __hip_bfloat16* __restrict__ W1bf,
                                               const int* __restrict__ deg,
                                               __hip_bfloat16* __restrict__ h1s) {
    const int lane = threadIdx.x & 63;
    const int wave = blockIdx.x * 4 + (threadIdx.x >> 6);
    const int row0 = wave * 64;
    if (row0 >= NN) return;
    const int q = lane >> 4, m = lane & 15;

    f32x4 acc[4][4];
#pragma unroll
    for (int i = 0; i < 4; ++i)
#pragma unroll
        for (int j = 0; j < 4; ++j) acc[i][j] = (f32x4){0.f, 0.f, 0.f, 0.f};

    for (int k0 = 0; k0 < NF; k0 += 32) {
        bf16x8 bfr[4];
#pragma unroll
        for (int ot = 0; ot < 4; ++ot)
            bfr[ot] = *reinterpret_cast<const bf16x8*>(W1bf + (ot * 16 + m) * NF + k0 + q * 8);
#pragma unroll
        for (int mt = 0; mt < 4; ++mt) {
            int r = row0 + mt * 16 + m;
            if (r > NN - 1) r = NN - 1;  // tail clamp (store guarded)
            bf16x8 afr = cvt8(x + (size_t)r * NF + k0 + q * 8);
#pragma unroll
            for (int ot = 0; ot < 4; ++ot)
                acc[mt][ot] = __builtin_amdgcn_mfma_f32_16x16x32_bf16(afr, bfr[ot], acc[mt][ot], 0, 0, 0);
        }
    }

#pragma unroll
    for (int mt = 0; mt < 4; ++mt)
#pragma unroll
        for (int rr = 0; rr < 4; ++rr) {
            int row = row0 + mt * 16 + q * 4 + rr;
            if (row < NN) {
                float di = rsqrtf((float)deg[row] + 1.0f);
#pragma unroll
                for (int ot = 0; ot < 4; ++ot)
                    h1s[row * NH + ot * 16 + m] = __float2bfloat16(acc[mt][ot][rr] * di);
            }
        }
}

// ---------------- gath1: bucket-block LDS aggregation of h1s -> r1s ----------
// r1s[n] = relu(dinv[n]*(sum_s h1s[s] + h1s[n]) + b1) * dinv[n]   (pre-scaled)
__global__ __launch_bounds__(512, 8) void k_gath1(const int* __restrict__ gcur,
                                                  const int* __restrict__ staging,
                                                  const int* __restrict__ deg,
                                                  const __hip_bfloat16* __restrict__ h1s,
                                                  const float* __restrict__ b1,
                                                  __hip_bfloat16* __restrict__ r1s) {
    __shared__ float acc[128 * 64];   // 32KB
    const int b = blockIdx.x, t = threadIdx.x;
    const int lane = t & 63, w = t >> 6;      // 8 waves
    const int count = gcur[b];
    const int sbase = b * CAP;
    for (int i = t; i < 128 * 64; i += 512) acc[i] = 0.f;
    __syncthreads();

    // edge phase: coalesced entry loads, shfl broadcast, 8-deep row-load ILP
    for (int base_i = w * 64; base_i < count; base_i += 512) {
        int idx = base_i + lane;
        int pv = (idx < count) ? staging[sbase + idx] : -1;
#pragma unroll
        for (int k = 0; k < 64; k += 8) {
            int p[8];
            float v[8];
#pragma unroll
            for (int u = 0; u < 8; ++u) p[u] = __shfl(pv, k + u);
#pragma unroll
            for (int u = 0; u < 8; ++u) {
                int s = (p[u] >= 0) ? (p[u] & 0x1FFFF) : 0;
                float vv = __bfloat162float(h1s[s * 64 + lane]);
                v[u] = (p[u] >= 0) ? vv : 0.f;
            }
#pragma unroll
            for (int u = 0; u < 8; ++u) {
                int d = (p[u] >= 0) ? (p[u] >> 17) : 0;
                atomicAdd(&acc[d * 64 + lane], v[u]);   // ds_add_f32, no return
            }
        }
    }
    __syncthreads();

    // epilogue: self-loop + norm + bias + relu + pre-scale, per owner wave
    const int nb = min(128, NN - b * 128);
    const float bias = b1[lane];
    for (int n0 = w; n0 < nb; n0 += 8) {
        const int node = b * 128 + n0;
        float a = acc[n0 * 64 + lane];
        float selfv = __bfloat162float(h1s[node * 64 + lane]);
        float dn = rsqrtf((float)deg[node] + 1.0f);
        float r = fmaxf((a + selfv) * dn + bias, 0.0f);
        r1s[node * 64 + lane] = __float2bfloat16(r * dn);
    }
}

// ---------------- gath2: aggregate r1s + fused 64->40 matvec -> out ----------
// out[n] = dinv[n] * ((sum_s r1s[s] + r1s[n]) @ W2^T) + b2
__global__ __launch_bounds__(512, 6) void k_gath2(const int* __restrict__ gcur,
                                                  const int* __restrict__ staging,
                                                  const int* __restrict__ deg,
                                                  const __hip_bfloat16* __restrict__ r1s,
                                                  const __hip_bfloat16* __restrict__ W2bf,
                                                  const float* __restrict__ b2,
                                                  float* __restrict__ out) {
    __shared__ float acc[128 * 64];    // 32KB
    __shared__ float W2l[40 * 65];     // 10.2KB, pad-65 -> (lane+k)%32 banks
    const int b = blockIdx.x, t = threadIdx.x;
    const int lane = t & 63, w = t >> 6;
    const int count = gcur[b];
    const int sbase = b * CAP;
    for (int i = t; i < 128 * 64; i += 512) acc[i] = 0.f;
    for (int i = t; i < NC * NH; i += 512)
        W2l[(i >> 6) * 65 + (i & 63)] = __bfloat162float(W2bf[i]);
    __syncthreads();

    for (int base_i = w * 64; base_i < count; base_i += 512) {
        int idx = base_i + lane;
        int pv = (idx < count) ? staging[sbase + idx] : -1;
#pragma unroll
        for (int k = 0; k < 64; k += 8) {
            int p[8];
            float v[8];
#pragma unroll
            for (int u = 0; u < 8; ++u) p[u] = __shfl(pv, k + u);
#pragma unroll
            for (int u = 0; u < 8; ++u) {
                int s = (p[u] >= 0) ? (p[u] & 0x1FFFF) : 0;
                float vv = __bfloat162float(r1s[s * 64 + lane]);
                v[u] = (p[u] >= 0) ? vv : 0.f;
            }
#pragma unroll
            for (int u = 0; u < 8; ++u) {
                int d = (p[u] >= 0) ? (p[u] >> 17) : 0;
                atomicAdd(&acc[d * 64 + lane], v[u]);
            }
        }
    }
    __syncthreads();

    // epilogue: + self row, then 64->40 matvec from LDS, scale, bias, store
    const int nb = min(128, NN - b * 128);
    const float bias = (lane < NC) ? b2[lane] : 0.f;
    for (int n0 = w; n0 < nb; n0 += 8) {
        const int node = b * 128 + n0;
        float selfv = __bfloat162float(r1s[node * 64 + lane]);
        acc[n0 * 64 + lane] += selfv;       // owner wave exclusive; in-wave ordered
        float dn = rsqrtf((float)deg[node] + 1.0f);
        if (lane < NC) {
            float o = 0.f;
#pragma unroll
            for (int k = 0; k < 64; ++k)
                o += acc[n0 * 64 + k] * W2l[lane * 65 + k];
            out[node * NC + lane] = o * dn + bias;
        }
    }
}

extern "C" void kernel_launch(void* const* d_in, const int* in_sizes, int n_in,
                              void* d_out, int out_size, void* d_ws, size_t ws_size,
                              hipStream_t stream) {
    const float* x  = (const float*)d_in[0];
    const int*   ei = (const int*)d_in[1];
    const float* W1 = (const float*)d_in[2];
    const float* b1 = (const float*)d_in[3];
    const float* W2 = (const float*)d_in[4];
    const float* b2 = (const float*)d_in[5];
    const int* srcp = ei;        // edge_index[0]
    const int* dstp = ei + NE;   // edge_index[1]

    char* ws = (char*)d_ws;
    int*            deg     = (int*)(ws + OFF_DEG);
    int*            gcur    = (int*)(ws + OFF_GCUR);
    __hip_bfloat16* W1bf    = (__hip_bfloat16*)(ws + OFF_W1BF);
    __hip_bfloat16* W2bf    = (__hip_bfloat16*)(ws + OFF_W2BF);
    int*            staging = (int*)(ws + OFF_STAGE);
    __hip_bfloat16* h1s     = (__hip_bfloat16*)(ws + OFF_H1);
    __hip_bfloat16* r1s     = (__hip_bfloat16*)(ws + OFF_R1);

    // --- weights to bf16 + zero deg/gcur ---
    k_cvtw<<<(NN + 255) / 256, 256, 0, stream>>>(W1, W2, W1bf, W2bf, gcur, deg);

    // --- bucket staging + degree histogram ---
    k_binA<<<ABLK, 256, 0, stream>>>(srcp, dstp, gcur, staging, deg);

    // --- layer 1 transform ---
    const int gemm_blocks = (NN + 255) / 256;   // 4 waves/block, 64 rows/wave
    k_gemm1<<<gemm_blocks, 256, 0, stream>>>(x, W1bf, deg, h1s);

    // --- layer 1 aggregate (+relu, pre-scale) ---
    k_gath1<<<NBUCK, 512, 0, stream>>>(gcur, staging, deg, h1s, b1, r1s);

    // --- layer 2 aggregate + fused matvec ---
    k_gath2<<<NBUCK, 512, 0, stream>>>(gcur, staging, deg, r1s, W2bf, b2,
                                       (float*)d_out);
}

// Round 5
// 500.029 us; speedup vs baseline: 3.7152x; 3.7152x over previous
//
#include <hip/hip_runtime.h>
#include <hip/hip_bf16.h>

// GCN 2-layer forward on MI355X (gfx950). fp32 in/out, int32 edges.
// Round 9: REVERT to round-7 structure (verified 499us; round-8's bucket-LDS
// aggregation was latency-serialized: 760us gath2 with 6% VALUBusy).
// Diagnostic from round 8: ~120-360us of dur_us is harness poison-fill of the
// 800MB workspace; our kernels sum to ~140-260us. Changes this round:
//   1. k_gemm1: 32 rows/wave (acc[2][4], 782 blocks = 3 blocks/CU, 12 waves/CU
//      vs 391 blocks = 6 waves/CU) + explicit f32x4-pair x loads (was 8 scalar
//      fp32 loads per fragment). x-read HBM floor = 33us.
//   2. k_binA: int4 vectorized dst/src reads (ABLK=250, CHUNK=6400, no tail).
// All other kernels byte-identical to the verified round-7 source.
// Round 10: identical resubmission (bench infra failed twice; no counters).

typedef __attribute__((ext_vector_type(8))) short bf16x8;   // 8 bf16 = 4 VGPRs
typedef __attribute__((ext_vector_type(4))) float f32x4;    // MFMA C/D

constexpr int NN = 100000;   // nodes
constexpr int NF = 512;      // input feats
constexpr int NH = 64;       // hidden
constexpr int NC = 40;       // classes
constexpr int NE = 1600000;  // edges

constexpr int NBUCK = 391;     // ceil(NN/256): bucket = dst >> 8
constexpr int CAP   = 6144;    // staging capacity/bucket (mean 4092, +32 sigma)
constexpr int ABLK  = 250;     // binA blocks
constexpr int CHUNK = NE / ABLK;  // 6400 edges/block (exact, /4 = 1600 int4)

// ---- ws layout (byte offsets) ----
constexpr size_t OFF_DINV   = 0;           // float[NN]
constexpr size_t OFF_ROWPTR = 524288;      // int[NN+1]
constexpr size_t OFF_GCUR   = 1048576;     // int[512] bucket totals (391 used)
constexpr size_t OFF_W1BF   = 1576960;     // bf16[64*512] = 64KB
constexpr size_t OFF_W2BF   = 1642496;     // bf16[40*64]
constexpr size_t OFF_EBUF   = 2097152;     // int[NE] CSR src ids, 6.4MB
constexpr size_t OFF_H1     = 9437184;     // bf16[NN*64] = 12.8MB (h2s reuses, padded)
constexpr size_t OFF_R1     = 23068672;    // bf16[NN*64] = 12.8MB
// staging int[NBUCK*CAP] = 9.61MB ALIASES h1s region (dead during CSR build)
constexpr size_t OFF_STAGE  = OFF_H1;

// fp32 -> bf16 fragment helpers
__device__ inline short f2bs(float f) {
    union { __hip_bfloat16 h; short s; } u;
    u.h = __float2bfloat16(f);
    return u.s;
}
// vectorized: two 16B fp32 loads -> 8 bf16
__device__ inline bf16x8 cvt8v(const float* __restrict__ p) {
    const f32x4* q4 = reinterpret_cast<const f32x4*>(p);
    f32x4 a = q4[0], b = q4[1];
    bf16x8 r;
#pragma unroll
    for (int i = 0; i < 4; ++i) { r[i] = f2bs(a[i]); r[i + 4] = f2bs(b[i]); }
    return r;
}

// ---------------- W1/W2 fp32 -> bf16 (once) + zero bucket cursors ----------
__global__ __launch_bounds__(256) void k_cvtw(const float* __restrict__ W1,
                                              const float* __restrict__ W2,
                                              __hip_bfloat16* __restrict__ W1bf,
                                              __hip_bfloat16* __restrict__ W2bf,
                                              int* __restrict__ gcur) {
    int i = blockIdx.x * 256 + threadIdx.x;
    if (i < NH * NF) W1bf[i] = __float2bfloat16(W1[i]);
    int j = i - NH * NF;
    if (j >= 0 && j < NC * NH) W2bf[j] = __float2bfloat16(W2[j]);
    if (i < 512) gcur[i] = 0;
}

// ---------------- binA: bucket edges by dst>>8, int4 reads, packed writes ----
__global__ __launch_bounds__(256) void k_binA(const int* __restrict__ src,
                                              const int* __restrict__ dst,
                                              int* __restrict__ gcur,
                                              int* __restrict__ staging) {
    __shared__ int cnt[NBUCK];
    __shared__ int base[NBUCK];
    __shared__ int cur[NBUCK];
    const int t = threadIdx.x;
    const int e0 = blockIdx.x * CHUNK;
    for (int i = t; i < NBUCK; i += 256) { cnt[i] = 0; cur[i] = 0; }
    __syncthreads();
    const int4* d4 = reinterpret_cast<const int4*>(dst + e0);
    const int4* s4 = reinterpret_cast<const int4*>(src + e0);
    for (int g = t; g < CHUNK / 4; g += 256) {
        int4 d = d4[g];
        atomicAdd(&cnt[d.x >> 8], 1);
        atomicAdd(&cnt[d.y >> 8], 1);
        atomicAdd(&cnt[d.z >> 8], 1);
        atomicAdd(&cnt[d.w >> 8], 1);
    }
    __syncthreads();
    for (int i = t; i < NBUCK; i += 256)
        base[i] = atomicAdd(&gcur[i], cnt[i]);   // reserve contiguous run
    __syncthreads();
    for (int g = t; g < CHUNK / 4; g += 256) {
        int4 d = d4[g];
        int4 s = s4[g];
        {
            int b = d.x >> 8; int r = atomicAdd(&cur[b], 1); int pos = base[b] + r;
            if (pos < CAP) staging[b * CAP + pos] = ((d.x & 255) << 17) | s.x;
        }
        {
            int b = d.y >> 8; int r = atomicAdd(&cur[b], 1); int pos = base[b] + r;
            if (pos < CAP) staging[b * CAP + pos] = ((d.y & 255) << 17) | s.y;
        }
        {
            int b = d.z >> 8; int r = atomicAdd(&cur[b], 1); int pos = base[b] + r;
            if (pos < CAP) staging[b * CAP + pos] = ((d.z & 255) << 17) | s.z;
        }
        {
            int b = d.w >> 8; int r = atomicAdd(&cur[b], 1); int pos = base[b] + r;
            if (pos < CAP) staging[b * CAP + pos] = ((d.w & 255) << 17) | s.w;
        }
    }
}

// ---------------- binB: per-bucket prefix + degree/rowptr/dinv + CSR scatter ----
__global__ __launch_bounds__(256) void k_binB(const int* __restrict__ gcur,
                                              const int* __restrict__ staging,
                                              int* __restrict__ rowptr,
                                              float* __restrict__ dinv,
                                              int* __restrict__ ebuf) {
    __shared__ int redbuf[256];
    __shared__ int hist[256];
    __shared__ int s[256];
    __shared__ int cur[256];
    const int b = blockIdx.x, t = threadIdx.x;
    const int count = gcur[b];
    const int sbase = b * CAP;

    // fused exclusive-prefix: base = sum(gcur[0..b))
    int acc0 = 0;
    if (t < b) acc0 = gcur[t];
    if (t + 256 < b) acc0 += gcur[t + 256];
    redbuf[t] = acc0;
    hist[t] = 0;
    __syncthreads();
    for (int off = 128; off > 0; off >>= 1) {
        if (t < off) redbuf[t] += redbuf[t + off];
        __syncthreads();
    }
    const int base = redbuf[0];

    // in-bucket histogram (= per-node degree)
    for (int i = t; i < count; i += 256)
        atomicAdd(&hist[staging[sbase + i] >> 17], 1);
    __syncthreads();
    int v = hist[t];
    s[t] = v;
    __syncthreads();
    for (int off = 1; off < 256; off <<= 1) {
        int tv = (t >= off) ? s[t - off] : 0;
        __syncthreads();
        s[t] += tv;
        __syncthreads();
    }
    const int excl = s[t] - v;           // local exclusive offset
    int n = b * 256 + t;
    if (n < NN) {
        rowptr[n] = base + excl;
        dinv[n] = rsqrtf((float)v + 1.0f);   // +1 = self-loop
    }
    if (b == 0 && t == 0) rowptr[NN] = NE;
    cur[t] = excl;
    __syncthreads();
    for (int i = t; i < count; i += 256) {
        int pv = staging[sbase + i];
        int p = atomicAdd(&cur[pv >> 17], 1);
        ebuf[base + p] = pv & 0x1FFFF;   // src id
    }
}

// ---------------- GEMM1: h1s[NN,64] = (x @ W1^T) * dinv[row]  (bf16) ----
// 32 rows/wave (782 blocks = ~3 blocks/CU, 12 waves/CU) for latency hiding.
__global__ __launch_bounds__(256) void k_gemm1(const float* __restrict__ x,
                                               const __hip_bfloat16* __restrict__ W1bf,
                                               const float* __restrict__ dinv,
                                               __hip_bfloat16* __restrict__ h1s) {
    const int lane = threadIdx.x & 63;
    const int wave = blockIdx.x * 4 + (threadIdx.x >> 6);
    const int row0 = wave * 32;
    if (row0 >= NN) return;
    const int q = lane >> 4, m = lane & 15;

    f32x4 acc[2][4];
#pragma unroll
    for (int i = 0; i < 2; ++i)
#pragma unroll
        for (int j = 0; j < 4; ++j) acc[i][j] = (f32x4){0.f, 0.f, 0.f, 0.f};

    for (int k0 = 0; k0 < NF; k0 += 32) {
        bf16x8 bfr[4];
#pragma unroll
        for (int ot = 0; ot < 4; ++ot)
            bfr[ot] = *reinterpret_cast<const bf16x8*>(W1bf + (ot * 16 + m) * NF + k0 + q * 8);
#pragma unroll
        for (int mt = 0; mt < 2; ++mt) {
            int r = row0 + mt * 16 + m;
            if (r > NN - 1) r = NN - 1;  // tail clamp (store guarded)
            bf16x8 afr = cvt8v(x + (size_t)r * NF + k0 + q * 8);
#pragma unroll
            for (int ot = 0; ot < 4; ++ot)
                acc[mt][ot] = __builtin_amdgcn_mfma_f32_16x16x32_bf16(afr, bfr[ot], acc[mt][ot], 0, 0, 0);
        }
    }

#pragma unroll
    for (int mt = 0; mt < 2; ++mt)
#pragma unroll
        for (int rr = 0; rr < 4; ++rr) {
            int row = row0 + mt * 16 + q * 4 + rr;
            if (row < NN) {
                float di = dinv[row];
#pragma unroll
                for (int ot = 0; ot < 4; ++ot)
                    h1s[row * NH + ot * 16 + m] = __float2bfloat16(acc[mt][ot][rr] * di);
            }
        }
}

// ---------------- gather1: r1[n] = relu(dn * (sum h1s[s] + h1s[n]) + b1) ----
__global__ __launch_bounds__(256) void k_gather1(const int* __restrict__ rowptr,
                                                 const int* __restrict__ ebuf,
                                                 const float* __restrict__ dinv,
                                                 const __hip_bfloat16* __restrict__ h1s,
                                                 const float* __restrict__ b1,
                                                 __hip_bfloat16* __restrict__ r1) {
    const int lane = threadIdx.x & 63;
    const int n = blockIdx.x * 4 + (threadIdx.x >> 6);
    if (n >= NN) return;
    const int beg = rowptr[n], end = rowptr[n + 1];
    // independent loads issued early: self-loop row + bias + dinv
    float selfv = __bfloat162float(h1s[n * NH + lane]);
    float bias = b1[lane];
    float dn = dinv[n];
    float acc = 0.0f;
    int j = beg;
    for (; j + 8 <= end; j += 8) {
        int e0 = ebuf[j + 0], e1 = ebuf[j + 1], e2 = ebuf[j + 2], e3 = ebuf[j + 3];
        int e4 = ebuf[j + 4], e5 = ebuf[j + 5], e6 = ebuf[j + 6], e7 = ebuf[j + 7];
        float v0 = __bfloat162float(h1s[e0 * NH + lane]);
        float v1 = __bfloat162float(h1s[e1 * NH + lane]);
        float v2 = __bfloat162float(h1s[e2 * NH + lane]);
        float v3 = __bfloat162float(h1s[e3 * NH + lane]);
        float v4 = __bfloat162float(h1s[e4 * NH + lane]);
        float v5 = __bfloat162float(h1s[e5 * NH + lane]);
        float v6 = __bfloat162float(h1s[e6 * NH + lane]);
        float v7 = __bfloat162float(h1s[e7 * NH + lane]);
        acc += ((v0 + v1) + (v2 + v3)) + ((v4 + v5) + (v6 + v7));
    }
    for (; j < end; ++j)
        acc += __bfloat162float(h1s[ebuf[j] * NH + lane]);
    acc += selfv;   // self-loop (pre-scaled)
    acc = acc * dn + bias;
    r1[n * NH + lane] = __float2bfloat16(fmaxf(acc, 0.0f));
}

// ---------------- GEMM2: h2s[NN,64pad] = (r1 @ W2^T) * dinv[row]  (bf16) ----
__global__ __launch_bounds__(256) void k_gemm2(const __hip_bfloat16* __restrict__ r1,
                                               const __hip_bfloat16* __restrict__ W2bf,
                                               const float* __restrict__ dinv,
                                               __hip_bfloat16* __restrict__ h2s) {
    const int lane = threadIdx.x & 63;
    const int wave = blockIdx.x * 4 + (threadIdx.x >> 6);
    const int row0 = wave * 64;
    if (row0 >= NN) return;
    const int q = lane >> 4, m = lane & 15;

    f32x4 acc[4][3];
#pragma unroll
    for (int i = 0; i < 4; ++i)
#pragma unroll
        for (int j = 0; j < 3; ++j) acc[i][j] = (f32x4){0.f, 0.f, 0.f, 0.f};

#pragma unroll
    for (int k0 = 0; k0 < NH; k0 += 32) {
        bf16x8 bfr[3];
#pragma unroll
        for (int ot = 0; ot < 3; ++ot) {
            int o = ot * 16 + m;
            if (o > NC - 1) o = NC - 1;  // stay inside W2's 40 rows
            bfr[ot] = *reinterpret_cast<const bf16x8*>(W2bf + o * NH + k0 + q * 8);
        }
#pragma unroll
        for (int mt = 0; mt < 4; ++mt) {
            int r = row0 + mt * 16 + m;
            if (r > NN - 1) r = NN - 1;
            bf16x8 afr = *reinterpret_cast<const bf16x8*>(r1 + r * NH + k0 + q * 8);
#pragma unroll
            for (int ot = 0; ot < 3; ++ot)
                acc[mt][ot] = __builtin_amdgcn_mfma_f32_16x16x32_bf16(afr, bfr[ot], acc[mt][ot], 0, 0, 0);
        }
    }

#pragma unroll
    for (int mt = 0; mt < 4; ++mt)
#pragma unroll
        for (int rr = 0; rr < 4; ++rr) {
            int row = row0 + mt * 16 + q * 4 + rr;
            if (row < NN) {
                float di = dinv[row];
#pragma unroll
                for (int ot = 0; ot < 3; ++ot) {
                    int col = ot * 16 + m;
                    if (col < NC) h2s[row * 64 + col] = __float2bfloat16(acc[mt][ot][rr] * di);
                }
            }
        }
}

// ---------------- gather2: out[n] = dn*(sum h2s[s] + h2s[n]) + b2 (fp32) ----
__global__ __launch_bounds__(256) void k_gather2(const int* __restrict__ rowptr,
                                                 const int* __restrict__ ebuf,
                                                 const float* __restrict__ dinv,
                                                 const __hip_bfloat16* __restrict__ h2s,
                                                 const float* __restrict__ b2,
                                                 float* __restrict__ out) {
    const int lane = threadIdx.x & 63;
    const int n = blockIdx.x * 4 + (threadIdx.x >> 6);
    if (n >= NN || lane >= NC) return;
    const int beg = rowptr[n], end = rowptr[n + 1];
    float selfv = __bfloat162float(h2s[n * 64 + lane]);
    float bias = b2[lane];
    float dn = dinv[n];
    float acc = 0.0f;
    int j = beg;
    for (; j + 8 <= end; j += 8) {
        int e0 = ebuf[j + 0], e1 = ebuf[j + 1], e2 = ebuf[j + 2], e3 = ebuf[j + 3];
        int e4 = ebuf[j + 4], e5 = ebuf[j + 5], e6 = ebuf[j + 6], e7 = ebuf[j + 7];
        float v0 = __bfloat162float(h2s[e0 * 64 + lane]);
        float v1 = __bfloat162float(h2s[e1 * 64 + lane]);
        float v2 = __bfloat162float(h2s[e2 * 64 + lane]);
        float v3 = __bfloat162float(h2s[e3 * 64 + lane]);
        float v4 = __bfloat162float(h2s[e4 * 64 + lane]);
        float v5 = __bfloat162float(h2s[e5 * 64 + lane]);
        float v6 = __bfloat162float(h2s[e6 * 64 + lane]);
        float v7 = __bfloat162float(h2s[e7 * 64 + lane]);
        acc += ((v0 + v1) + (v2 + v3)) + ((v4 + v5) + (v6 + v7));
    }
    for (; j < end; ++j)
        acc += __bfloat162float(h2s[ebuf[j] * 64 + lane]);
    acc += selfv;   // self-loop (pre-scaled)
    out[n * NC + lane] = acc * dn + bias;
}

extern "C" void kernel_launch(void* const* d_in, const int* in_sizes, int n_in,
                              void* d_out, int out_size, void* d_ws, size_t ws_size,
                              hipStream_t stream) {
    const float* x  = (const float*)d_in[0];
    const int*   ei = (const int*)d_in[1];
    const float* W1 = (const float*)d_in[2];
    const float* b1 = (const float*)d_in[3];
    const float* W2 = (const float*)d_in[4];
    const float* b2 = (const float*)d_in[5];
    const int* srcp = ei;        // edge_index[0]
    const int* dstp = ei + NE;   // edge_index[1]

    char* ws = (char*)d_ws;
    float*          dinv    = (float*)(ws + OFF_DINV);
    int*            rowptr  = (int*)(ws + OFF_ROWPTR);
    int*            gcur    = (int*)(ws + OFF_GCUR);
    __hip_bfloat16* W1bf    = (__hip_bfloat16*)(ws + OFF_W1BF);
    __hip_bfloat16* W2bf    = (__hip_bfloat16*)(ws + OFF_W2BF);
    int*            ebuf    = (int*)(ws + OFF_EBUF);
    int*            staging = (int*)(ws + OFF_STAGE);          // aliases h1s
    __hip_bfloat16* h1s     = (__hip_bfloat16*)(ws + OFF_H1);  // h2s reuses
    __hip_bfloat16* r1      = (__hip_bfloat16*)(ws + OFF_R1);

    // --- weights to bf16 + zero bucket cursors ---
    k_cvtw<<<(NH * NF + NC * NH + 255) / 256, 256, 0, stream>>>(W1, W2, W1bf, W2bf, gcur);

    // --- CSR build: two-level bucket sort (staging aliases h1s, dead here) ---
    k_binA<<<ABLK, 256, 0, stream>>>(srcp, dstp, gcur, staging);
    k_binB<<<NBUCK, 256, 0, stream>>>(gcur, staging, rowptr, dinv, ebuf);

    const int g1_blocks = ((NN + 31) / 32 + 3) / 4;   // 782: 4 waves, 32 rows/wave
    const int g2_blocks = ((NN + 63) / 64 + 3) / 4;   // 391: 4 waves, 64 rows/wave
    const int node_blocks = (NN + 3) / 4;             // 4 waves/block, 1 node/wave

    // --- layer 1 ---
    k_gemm1<<<g1_blocks, 256, 0, stream>>>(x, W1bf, dinv, h1s);
    k_gather1<<<node_blocks, 256, 0, stream>>>(rowptr, ebuf, dinv, h1s, b1, r1);

    // --- layer 2 (h2s reuses h1s's buffer, rows padded to 64) ---
    __hip_bfloat16* h2s = h1s;
    k_gemm2<<<g2_blocks, 256, 0, stream>>>(r1, W2bf, dinv, h2s);
    k_gather2<<<node_blocks, 256, 0, stream>>>(rowptr, ebuf, dinv, h2s, b2,
                                               (float*)d_out);
}